// Round 1
// 4833.775 us; speedup vs baseline: 1.0882x; 1.0882x over previous
//
#include <hip/hip_runtime.h>
#include <stdint.h>

#define NN 9216     // tokens = 96*96
#define CCH 1024    // channels
#define KK 64       // clusters
#define HP 96       // patch grid
#define SCALE 14
#define HH 1344     // output H=W
#define NUM_ITERS 30
#define TOLV 1e-4

// ---------------- Threefry-2x32-20 block ----------------
__device__ __forceinline__ void tf2x32(unsigned k0, unsigned k1, unsigned& x0, unsigned& x1) {
  unsigned ks2 = k0 ^ k1 ^ 0x1BD11BDAu;
  x0 += k0; x1 += k1;
#define TFR(r) { x0 += x1; x1 = (x1 << r) | (x1 >> (32 - r)); x1 ^= x0; }
  TFR(13) TFR(15) TFR(26) TFR(6)
  x0 += k1; x1 += ks2 + 1u;
  TFR(17) TFR(29) TFR(16) TFR(24)
  x0 += ks2; x1 += k0 + 2u;
  TFR(13) TFR(15) TFR(26) TFR(6)
  x0 += k0; x1 += k1 + 3u;
  TFR(17) TFR(29) TFR(16) TFR(24)
  x0 += k1; x1 += ks2 + 4u;
  TFR(13) TFR(15) TFR(26) TFR(6)
  x0 += ks2; x1 += k0 + 5u;
#undef TFR
}

// jax_threefry_partitionable semantics; 36 blocks x 256. Also zeroes ssq.
__global__ __launch_bounds__(256) void k_rng(unsigned* bits1, unsigned* bits2, double* ssq) {
  int t = blockIdx.x * 256 + threadIdx.x;      // 0..9215
  unsigned k1a = 0, k1b = 0; tf2x32(0u, 42u, k1a, k1b);   // key1 = block(key0; 0,0)
  unsigned s1a = 0, s1b = 1; tf2x32(0u, 42u, s1a, s1b);   // subkey1 = block(key0; 0,1)
  unsigned s2a = 0, s2b = 1; tf2x32(k1a, k1b, s2a, s2b);  // subkey2 = block(key1; 0,1)
  unsigned o0 = 0, o1 = (unsigned)t;
  tf2x32(s1a, s1b, o0, o1);
  bits1[t] = o0 ^ o1;
  o0 = 0; o1 = (unsigned)t;
  tf2x32(s2a, s2b, o0, o1);
  bits2[t] = o0 ^ o1;
  ssq[t] = 0.0;
}

// stable-sort rank (O(N^2) with LDS broadcast). 36 blocks x 256.
__global__ __launch_bounds__(256) void k_rank(const unsigned* __restrict__ bits,
                                              const unsigned* __restrict__ vals,
                                              unsigned* __restrict__ out_perm) {
  __shared__ __align__(16) unsigned lb[NN];
  int tid = threadIdx.x;
  for (int idx = tid; idx < NN; idx += 256) lb[idx] = bits[idx];
  __syncthreads();
  int i = blockIdx.x * 256 + tid;
  unsigned kb = lb[i];
  const uint4* l4 = reinterpret_cast<const uint4*>(lb);
  int rank = 0;
  for (int jj = 0; jj < NN / 4; ++jj) {
    uint4 v = l4[jj];
    int j = jj * 4;
    rank += (v.x < kb) || (v.x == kb && (j + 0) < i);
    rank += (v.y < kb) || (v.y == kb && (j + 1) < i);
    rank += (v.z < kb) || (v.z == kb && (j + 2) < i);
    rank += (v.w < kb) || (v.w == kb && (j + 3) < i);
  }
  out_perm[rank] = vals ? vals[i] : (unsigned)i;
}

// centers0[k][c] = X[idx[k]][c] (f32, exact). 64 blocks x 256.
__global__ __launch_bounds__(256) void k_gather(const float* __restrict__ F,
                                                const unsigned* __restrict__ perm2,
                                                float* __restrict__ centers) {
  int k = blockIdx.x;
  unsigned n = perm2[k];
  for (int c = threadIdx.x; c < CCH; c += 256)
    centers[k * CCH + c] = F[(size_t)c * NN + n];
}

// exact f64 sum of squares per token. grid (36,16) x 256.
__global__ __launch_bounds__(256) void k_ssq(const float* __restrict__ F, double* __restrict__ ssq) {
  int n = blockIdx.x * 256 + threadIdx.x;
  int c0 = blockIdx.y * 64;
  double acc = 0.0;
#pragma unroll 4
  for (int ci = 0; ci < 64; ++ci) {
    double v = (double)F[(size_t)(c0 + ci) * NN + n];
    acc = fma(v, v, acc);
  }
  atomicAdd(&ssq[n], acc);
}

// correctly-rounded f32 norm per token
__global__ __launch_bounds__(256) void k_norm32(const double* __restrict__ ssq, float* __restrict__ n32) {
  int n = blockIdx.x * 256 + threadIdx.x;
  n32[n] = (float)sqrt(ssq[n]);
}

// normalize f32 centers -> cnT[c][k] (f32 division); zero counts; done latch. 64 blocks x 256.
// NOTE: sums[] zero-fill removed — k_segsum overwrites every entry unconditionally.
__global__ __launch_bounds__(256) void k_prep(const float* __restrict__ centers,
                                              float* __restrict__ cnT,
                                              double* __restrict__ sums,
                                              int* __restrict__ counts,
                                              double* __restrict__ shift,
                                              int* __restrict__ done, int iter) {
  __shared__ double red[256];
  int k = blockIdx.x, tid = threadIdx.x;
  double local = 0.0;
  for (int c = tid; c < CCH; c += 256) {
    double v = (double)centers[k * CCH + c];
    local = fma(v, v, local);
  }
  red[tid] = local; __syncthreads();
  for (int s = 128; s > 0; s >>= 1) { if (tid < s) red[tid] += red[tid + s]; __syncthreads(); }
  float nc = fmaxf((float)sqrt(red[0]), 1e-10f);
  for (int c = tid; c < CCH; c += 256) {
    cnT[(size_t)c * KK + k] = centers[k * CCH + c] / nc;   // f32 division, like reference
  }
  if (tid == 0) {
    counts[k] = 0;
    if (k == 0) {
      if (iter == 0) { *done = 0; *shift = 0.0; }
      else { double s = *shift; if (s * s < TOLV) *done = 1; *shift = 0.0; }
    }
  }
}

// scores[n][k] = Xn32[n]·cn32[k], exact f64 accumulation of f32-rounded inputs.
// Software-pipelined: B tile via async global_load_lds DMA (LDS layout is tid*16-linear),
// A tile prefetched to regs (f32 division kept in staging to match reference Xn rounding),
// double-buffered LDS. FMA order identical to previous version -> bitwise-identical scores.
// MODE0: argmin -> assign+counts. MODE1: write f32 logitsS[k][n]. 288 blocks x 256.
template <int MODE>
__global__ __launch_bounds__(256) void k_assign(const float* __restrict__ F,
                                                const float* __restrict__ n32,
                                                const float* __restrict__ cnT,
                                                int* __restrict__ assign,
                                                int* __restrict__ counts,
                                                float* __restrict__ logitsS) {
  constexpr int TN = 32, CK = 32, NT = CCH / CK;
  __shared__ __align__(16) float As[2][CK][TN];   // 2 x 4 KB
  __shared__ __align__(16) float Bs[2][CK][KK];   // 2 x 8 KB
  const int tid = threadIdx.x;
  const int n0 = blockIdx.x * TN;
  const int a_ci = tid >> 3, a_nq = tid & 7;      // A staging
  const int b_ci = tid >> 4, b_kq = tid & 15;     // B staging
  const int nq = tid & 7, kp = tid >> 3;          // compute mapping
  const float* np4 = n32 + n0 + 4 * a_nq;
  float d0 = fmaxf(np4[0], 1e-10f), d1 = fmaxf(np4[1], 1e-10f);
  float d2 = fmaxf(np4[2], 1e-10f), d3 = fmaxf(np4[3], 1e-10f);
  double acc[4][2] = {{0, 0}, {0, 0}, {0, 0}, {0, 0}};

  // ---- prologue: stage tile 0 into buffer 0 ----
  {
    const float* g0 = cnT + (size_t)(b_ci) * KK + 4 * b_kq;
    const float* g1 = cnT + (size_t)(16 + b_ci) * KK + 4 * b_kq;
    float* l0 = &Bs[0][0][0] + tid * 4;
    float* l1 = &Bs[0][0][0] + 1024 + tid * 4;
    __builtin_amdgcn_global_load_lds((const __attribute__((address_space(1))) void*)g0,
                                     (__attribute__((address_space(3))) void*)l0, 16, 0, 0);
    __builtin_amdgcn_global_load_lds((const __attribute__((address_space(1))) void*)g1,
                                     (__attribute__((address_space(3))) void*)l1, 16, 0, 0);
    float4 va = *(const float4*)(F + (size_t)a_ci * NN + n0 + 4 * a_nq);
    float4 w;
    w.x = va.x / d0; w.y = va.y / d1; w.z = va.z / d2; w.w = va.w / d3;
    *(float4*)(&As[0][0][0] + tid * 4) = w;
  }
  __syncthreads();   // drains DMA (vmcnt) + ds_write (lgkmcnt)

  for (int t = 0; t < NT; ++t) {
    const int buf = t & 1, nbuf = buf ^ 1;
    float4 va;
    if (t + 1 < NT) {
      const int cc = CK * (t + 1);
      const float* g0 = cnT + (size_t)(cc + b_ci) * KK + 4 * b_kq;
      const float* g1 = cnT + (size_t)(cc + 16 + b_ci) * KK + 4 * b_kq;
      float* l0 = &Bs[nbuf][0][0] + tid * 4;
      float* l1 = &Bs[nbuf][0][0] + 1024 + tid * 4;
      __builtin_amdgcn_global_load_lds((const __attribute__((address_space(1))) void*)g0,
                                       (__attribute__((address_space(3))) void*)l0, 16, 0, 0);
      __builtin_amdgcn_global_load_lds((const __attribute__((address_space(1))) void*)g1,
                                       (__attribute__((address_space(3))) void*)l1, 16, 0, 0);
      va = *(const float4*)(F + (size_t)(cc + a_ci) * NN + n0 + 4 * a_nq);
    }
#pragma unroll 8
    for (int ci = 0; ci < CK; ++ci) {
      double b0 = (double)Bs[buf][ci][2 * kp + 0], b1 = (double)Bs[buf][ci][2 * kp + 1];
      double a0 = (double)As[buf][ci][4 * nq + 0], a1 = (double)As[buf][ci][4 * nq + 1];
      double a2 = (double)As[buf][ci][4 * nq + 2], a3 = (double)As[buf][ci][4 * nq + 3];
      acc[0][0] = fma(a0, b0, acc[0][0]); acc[0][1] = fma(a0, b1, acc[0][1]);
      acc[1][0] = fma(a1, b0, acc[1][0]); acc[1][1] = fma(a1, b1, acc[1][1]);
      acc[2][0] = fma(a2, b0, acc[2][0]); acc[2][1] = fma(a2, b1, acc[2][1]);
      acc[3][0] = fma(a3, b0, acc[3][0]); acc[3][1] = fma(a3, b1, acc[3][1]);
    }
    if (t + 1 < NT) {
      float4 w;
      w.x = va.x / d0; w.y = va.y / d1; w.z = va.z / d2; w.w = va.w / d3;
      *(float4*)(&As[nbuf][0][0] + tid * 4) = w;
    }
    __syncthreads();
  }

  float* Sl = &Bs[0][0][0];   // [TN][KK] f32 scores
#pragma unroll
  for (int r = 0; r < 4; ++r) {
    Sl[(4 * nq + r) * KK + 2 * kp + 0] = (float)acc[r][0];
    Sl[(4 * nq + r) * KK + 2 * kp + 1] = (float)acc[r][1];
  }
  __syncthreads();
  if (MODE == 0) {
    if (tid < TN) {
      const float* row = &Sl[tid * KK];
      float best = 1.0f - row[0]; int bk = 0;   // f32 "1 - sim": ties resolve to first index
      for (int k = 1; k < KK; ++k) { float d = 1.0f - row[k]; if (d < best) { best = d; bk = k; } }
      assign[n0 + tid] = bk;
      atomicAdd(&counts[bk], 1);
    }
  } else {
    for (int idx = tid; idx < TN * KK; idx += 256) {
      int k = idx >> 5, nj = idx & 31;
      logitsS[(size_t)k * NN + n0 + nj] = Sl[nj * KK + k];
    }
  }
}

// per-channel exact f64 segment sum of UNNORMALIZED X. 1024 blocks x 256.
// 8 replicated bin copies (padded to 66 for bank spread) cut LDS-atomic serialization ~8x.
__global__ __launch_bounds__(256) void k_segsum(const float* __restrict__ F,
                                                const int* __restrict__ assign,
                                                double* __restrict__ sums) {
  constexpr int NCOPY = 8, KP = KK + 2;
  __shared__ double bins[NCOPY][KP];   // 4.125 KB
  int c = blockIdx.x, tid = threadIdx.x;
  int cp = tid & (NCOPY - 1);
  for (int idx = tid; idx < NCOPY * KP; idx += 256) (&bins[0][0])[idx] = 0.0;
  __syncthreads();
  for (int n = tid; n < NN; n += 256) {
    int a = assign[n];
    double v = (double)F[(size_t)c * NN + n];
    atomicAdd(&bins[cp][a], v);
  }
  __syncthreads();
  if (tid < KK) {
    double s = 0.0;
#pragma unroll
    for (int r = 0; r < NCOPY; ++r) s += bins[r][tid];
    sums[(size_t)tid * CCH + c] = s;
  }
}

// center update (f32 stored, correctly-rounded mean) + shift. 64 blocks x 256.
__global__ __launch_bounds__(256) void k_update(float* __restrict__ centers,
                                                const double* __restrict__ sums,
                                                const int* __restrict__ counts,
                                                double* __restrict__ shift,
                                                const int* __restrict__ done) {
  if (*done) return;
  __shared__ double red[256];
  int k = blockIdx.x, tid = threadIdx.x;
  int cnt = counts[k];
  double local = 0.0;
  for (int c = tid; c < CCH; c += 256) {
    float old = centers[k * CCH + c];
    float nc = (cnt > 0) ? (float)(sums[k * CCH + c] / (double)cnt) : old;
    double d = (double)nc - (double)old;
    local = fma(d, d, local);
    centers[k * CCH + c] = nc;
  }
  red[tid] = local; __syncthreads();
  for (int s = 128; s > 0; s >>= 1) { if (tid < s) red[tid] += red[tid + s]; __syncthreads(); }
  if (tid == 0) atomicAdd(shift, sqrt(red[0]));
}

// fused bilinear x14 upsample + argmax, all-f32 mimicking jax resize.
// One block per OUTPUT ROW: stage the 2 needed input rows x 64 k in LDS, then every
// thread writes lane-consecutive pixels -> fully-coalesced full-cacheline stores.
// fmaf sequence / edge renorm / argmax tie order identical to previous version.
__global__ __launch_bounds__(256) void k_upsample(const float* __restrict__ logitsS,
                                                  float* __restrict__ out) {
  __shared__ float P[2][KK][HP];   // 48 KB
  const int oy = blockIdx.x;
  const int tid = threadIdx.x;
  const float inv = 1.0f / 14.0f;
  float s_y = ((float)oy + 0.5f) * inv - 0.5f;
  float fy = floorf(s_y);
  float wy1 = s_y - fy, wy0 = 1.0f - wy1;
  int y0 = (int)fy, y1 = y0 + 1;
  if (y0 < 0)      { y0 = 0;      y1 = 0;      wy0 = 1.0f; wy1 = 0.0f; }  // edge renorm
  if (y1 > HP - 1) { y0 = HP - 1; y1 = HP - 1; wy0 = 1.0f; wy1 = 0.0f; }
  for (int idx = tid; idx < 2 * KK * HP; idx += 256) {
    int r = idx / (KK * HP);
    int rem = idx - r * (KK * HP);
    int k = rem / HP, x = rem - k * HP;
    P[r][k][x] = logitsS[(size_t)k * NN + (r ? y1 : y0) * HP + x];
  }
  __syncthreads();
  float* outL = out + (size_t)HH * HH;
  const size_t rowoff = (size_t)oy * HH;
  for (int j = 0; j < 6; ++j) {
    int ox = tid + 256 * j;
    if (ox >= HH) break;                         // uniform per wave (only wave 0 runs j=5)
    float s_x = ((float)ox + 0.5f) * inv - 0.5f;
    float fx = floorf(s_x);
    float wx1 = s_x - fx, wx0 = 1.0f - wx1;
    int x0 = (int)fx, x1 = x0 + 1;
    if (x0 < 0)      { x0 = 0;      x1 = 0;      wx0 = 1.0f; wx1 = 0.0f; }
    if (x1 > HP - 1) { x0 = HP - 1; x1 = HP - 1; wx0 = 1.0f; wx1 = 0.0f; }
    float best = 0.0f; int bk = 0;
    for (int k = 0; k < KK; ++k) {
      float t0 = fmaf(wy1, P[1][k][x0], wy0 * P[0][k][x0]);
      float t1 = fmaf(wy1, P[1][k][x1], wy0 * P[0][k][x1]);
      float v  = fmaf(wx1, t1, wx0 * t0);
      outL[(size_t)k * (HH * HH) + rowoff + ox] = v;
      if (k == 0 || v > best) { best = v; bk = k; }
    }
    out[rowoff + ox] = (float)bk;
  }
}

extern "C" void kernel_launch(void* const* d_in, const int* in_sizes, int n_in,
                              void* d_out, int out_size, void* d_ws, size_t ws_size,
                              hipStream_t stream) {
  const float* F = (const float*)d_in[0];
  float* out = (float*)d_out;
  char* ws = (char*)d_ws;
  // workspace layout (bytes)
  double*   ssq     = (double*)(ws + 0);         // 9216 d
  float*    n32     = (float*)(ws + 73728);      // 9216 f
  float*    centers = (float*)(ws + 110592);     // 64*1024 f
  float*    cnT     = (float*)(ws + 372736);     // 1024*64 f
  double*   sums    = (double*)(ws + 634880);    // 64*1024 d
  float*    logitsS = (float*)(ws + 1159168);    // 64*9216 f
  double*   shift   = (double*)(ws + 3518464);   // 1 d
  unsigned* bits1   = (unsigned*)(ws + 3518472);
  unsigned* bits2   = (unsigned*)(ws + 3555336);
  unsigned* perm1   = (unsigned*)(ws + 3592200);
  unsigned* perm2   = (unsigned*)(ws + 3629064);
  int*      assign  = (int*)(ws + 3665928);
  int*      counts  = (int*)(ws + 3702792);
  int*      done    = (int*)(ws + 3703048);

  k_rng<<<36, 256, 0, stream>>>(bits1, bits2, ssq);
  k_rank<<<36, 256, 0, stream>>>(bits1, nullptr, perm1);
  k_rank<<<36, 256, 0, stream>>>(bits2, perm1, perm2);
  k_gather<<<64, 256, 0, stream>>>(F, perm2, centers);
  k_ssq<<<dim3(36, 16), 256, 0, stream>>>(F, ssq);
  k_norm32<<<36, 256, 0, stream>>>(ssq, n32);

  for (int it = 0; it <= NUM_ITERS; ++it) {
    k_prep<<<64, 256, 0, stream>>>(centers, cnT, sums, counts, shift, done, it);
    if (it == NUM_ITERS) break;
    k_assign<0><<<288, 256, 0, stream>>>(F, n32, cnT, assign, counts, logitsS);
    k_segsum<<<1024, 256, 0, stream>>>(F, assign, sums);
    k_update<<<64, 256, 0, stream>>>(centers, sums, counts, shift, done);
  }
  k_assign<1><<<288, 256, 0, stream>>>(F, n32, cnT, assign, counts, logitsS);
  k_upsample<<<1344, 256, 0, stream>>>(logitsS, out);
}

// Round 3
// 2662.849 us; speedup vs baseline: 1.9753x; 1.8153x over previous
//
#include <hip/hip_runtime.h>
#include <stdint.h>

#define NN 9216     // tokens = 96*96
#define CCH 1024    // channels
#define KK 64       // clusters
#define HP 96       // patch grid
#define SCALE 14
#define HH 1344     // output H=W
#define NUM_ITERS 30
#define TOLV 1e-4

typedef __attribute__((ext_vector_type(4))) double d4;

// ---------------- Threefry-2x32-20 block ----------------
__device__ __forceinline__ void tf2x32(unsigned k0, unsigned k1, unsigned& x0, unsigned& x1) {
  unsigned ks2 = k0 ^ k1 ^ 0x1BD11BDAu;
  x0 += k0; x1 += k1;
#define TFR(r) { x0 += x1; x1 = (x1 << r) | (x1 >> (32 - r)); x1 ^= x0; }
  TFR(13) TFR(15) TFR(26) TFR(6)
  x0 += k1; x1 += ks2 + 1u;
  TFR(17) TFR(29) TFR(16) TFR(24)
  x0 += ks2; x1 += k0 + 2u;
  TFR(13) TFR(15) TFR(26) TFR(6)
  x0 += k0; x1 += k1 + 3u;
  TFR(17) TFR(29) TFR(16) TFR(24)
  x0 += k1; x1 += ks2 + 4u;
  TFR(13) TFR(15) TFR(26) TFR(6)
  x0 += ks2; x1 += k0 + 5u;
#undef TFR
}

// jax_threefry_partitionable semantics; 36 blocks x 256. Also zeroes ssq.
__global__ __launch_bounds__(256) void k_rng(unsigned* bits1, unsigned* bits2, double* ssq) {
  int t = blockIdx.x * 256 + threadIdx.x;      // 0..9215
  unsigned k1a = 0, k1b = 0; tf2x32(0u, 42u, k1a, k1b);
  unsigned s1a = 0, s1b = 1; tf2x32(0u, 42u, s1a, s1b);
  unsigned s2a = 0, s2b = 1; tf2x32(k1a, k1b, s2a, s2b);
  unsigned o0 = 0, o1 = (unsigned)t;
  tf2x32(s1a, s1b, o0, o1);
  bits1[t] = o0 ^ o1;
  o0 = 0; o1 = (unsigned)t;
  tf2x32(s2a, s2b, o0, o1);
  bits2[t] = o0 ^ o1;
  ssq[t] = 0.0;
}

// stable-sort rank (O(N^2) with LDS broadcast). 36 blocks x 256.
__global__ __launch_bounds__(256) void k_rank(const unsigned* __restrict__ bits,
                                              const unsigned* __restrict__ vals,
                                              unsigned* __restrict__ out_perm) {
  __shared__ __align__(16) unsigned lb[NN];
  int tid = threadIdx.x;
  for (int idx = tid; idx < NN; idx += 256) lb[idx] = bits[idx];
  __syncthreads();
  int i = blockIdx.x * 256 + tid;
  unsigned kb = lb[i];
  const uint4* l4 = reinterpret_cast<const uint4*>(lb);
  int rank = 0;
  for (int jj = 0; jj < NN / 4; ++jj) {
    uint4 v = l4[jj];
    int j = jj * 4;
    rank += (v.x < kb) || (v.x == kb && (j + 0) < i);
    rank += (v.y < kb) || (v.y == kb && (j + 1) < i);
    rank += (v.z < kb) || (v.z == kb && (j + 2) < i);
    rank += (v.w < kb) || (v.w == kb && (j + 3) < i);
  }
  out_perm[rank] = vals ? vals[i] : (unsigned)i;
}

// centers0[k][c] = X[idx[k]][c] (f32, exact). 64 blocks x 256.
__global__ __launch_bounds__(256) void k_gather(const float* __restrict__ F,
                                                const unsigned* __restrict__ perm2,
                                                float* __restrict__ centers) {
  int k = blockIdx.x;
  unsigned n = perm2[k];
  for (int c = threadIdx.x; c < CCH; c += 256)
    centers[k * CCH + c] = F[(size_t)c * NN + n];
}

// exact f64 sum of squares per token. grid (36,16) x 256.
__global__ __launch_bounds__(256) void k_ssq(const float* __restrict__ F, double* __restrict__ ssq) {
  int n = blockIdx.x * 256 + threadIdx.x;
  int c0 = blockIdx.y * 64;
  double acc = 0.0;
#pragma unroll 4
  for (int ci = 0; ci < 64; ++ci) {
    double v = (double)F[(size_t)(c0 + ci) * NN + n];
    acc = fma(v, v, acc);
  }
  atomicAdd(&ssq[n], acc);
}

__global__ __launch_bounds__(256) void k_norm32(const double* __restrict__ ssq, float* __restrict__ n32) {
  int n = blockIdx.x * 256 + threadIdx.x;
  n32[n] = (float)sqrt(ssq[n]);
}

// One-time init (iter 0): cnT from gathered centers; zero counts/shift/done.
__global__ __launch_bounds__(256) void k_prep0(const float* __restrict__ centers,
                                               float* __restrict__ cnT,
                                               int* __restrict__ counts,
                                               double* __restrict__ shift,
                                               int* __restrict__ done) {
  __shared__ double red[256];
  int k = blockIdx.x, tid = threadIdx.x;
  double local = 0.0;
  for (int c = tid; c < CCH; c += 256) {
    double v = (double)centers[k * CCH + c];
    local = fma(v, v, local);
  }
  red[tid] = local; __syncthreads();
  for (int s = 128; s > 0; s >>= 1) { if (tid < s) red[tid] += red[tid + s]; __syncthreads(); }
  float nc = fmaxf((float)sqrt(red[0]), 1e-10f);
  for (int c = tid; c < CCH; c += 256)
    cnT[(size_t)c * KK + k] = centers[k * CCH + c] / nc;
  if (tid == 0) {
    counts[k] = 0;
    if (k == 0) { *done = 0; shift[0] = 0.0; shift[1] = 0.0; }
  }
}

// ---- MFMA f64 layout probe. 1 block x 64. All-exact power-of-2 probes. ----
// P1: A=2^lane,B=1 -> each D elem = 2^i * (1+2^16+2^32+2^48)  -> discovers D-row i,
//     validates A row-grouping (iA(l)=l&15).
// P2: symmetric -> D-col j, validates B col-grouping (jB(l)=l&15).
// P3: A=2^(l>>4), B=2^(10*(l>>4)) -> every D elem = 1+2^11+2^22+2^33 iff the
//     A/B k-pairing is straight (kA(l)=kB(l)=l>>4).
// okm=1 only if all probes decode AND the map differs from the round-2 assumption
// (if it matched, round-2 would have passed -> bug elsewhere -> don't trust MFMA).
__global__ void k_probe(int* __restrict__ rowT, int* __restrict__ colT, int* __restrict__ okm) {
  int l = threadIdx.x;
  d4 z = {0.0, 0.0, 0.0, 0.0};
  d4 v1 = __builtin_amdgcn_mfma_f64_16x16x4f64(ldexp(1.0, l), 1.0, z, 0, 0, 0);
  d4 v2 = __builtin_amdgcn_mfma_f64_16x16x4f64(1.0, ldexp(1.0, l), z, 0, 0, 0);
  d4 v3 = __builtin_amdgcn_mfma_f64_16x16x4f64(ldexp(1.0, l >> 4), ldexp(1.0, 10 * (l >> 4)), z, 0, 0, 0);
  const double CM = 281479271743489.0;      // 1+2^16+2^32+2^48 (exact, 49 bits)
  const double P3 = 8594130945.0;           // 1+2^11+2^22+2^33 (exact, 34 bits)
  bool good = true, ish1 = true;
#pragma unroll
  for (int r = 0; r < 4; ++r) {
    int i = -1, j = -1;
    for (int t = 0; t < 16; ++t) {
      if (v1[r] == ldexp(CM, t)) i = t;
      if (v2[r] == ldexp(CM, t)) j = t;
    }
    good = good && (i >= 0) && (j >= 0) && (v3[r] == P3);
    ish1 = ish1 && (i == 4 * (l >> 4) + r) && (j == (l & 15));
    rowT[4 * l + r] = i; colT[4 * l + r] = j;
  }
  unsigned long long mg = __ballot(good);
  unsigned long long mh = __ballot(ish1);
  if (l == 0) *okm = (mg == ~0ull && mh != ~0ull) ? 1 : 0;
}

// ---- MFMA-f64 assign: active iff *okm==1. D placed via probed tables. ----
template <int MODE>
__global__ __launch_bounds__(256) void k_assign_m(const float* __restrict__ F,
                                                  const float* __restrict__ n32,
                                                  const float* __restrict__ cnT,
                                                  int* __restrict__ assign,
                                                  int* __restrict__ counts,
                                                  float* __restrict__ logitsS,
                                                  double* __restrict__ shift,
                                                  const int* __restrict__ done,
                                                  const int* __restrict__ rowT,
                                                  const int* __restrict__ colT,
                                                  const int* __restrict__ okm,
                                                  int iter) {
  if (*okm == 0) return;
  constexpr int CK = 64, NT = CCH / CK;
  constexpr int ASTR = 40, BSTR = 72;
  __shared__ __align__(16) float As[2][CK][ASTR];
  __shared__ __align__(16) float Bs[2][CK][BSTR];
  const int tid = threadIdx.x;
  if (MODE == 0) {
    if (blockIdx.x == 0 && tid == 0) shift[iter & 1] = 0.0;
    if (*done) return;
  }
  const int n0 = blockIdx.x * 32;
  const int s_ci = tid >> 2, s_q = tid & 3;
  const int lane = tid & 63, w = tid >> 6;
  const int h = w & 1, q = w >> 1;
  const int arow  = h * 16 + (lane & 15);
  const int kq    = lane >> 4;
  const int bcol0 = q * 32 + (lane & 15);
  float dn[8];
#pragma unroll
  for (int j = 0; j < 4; ++j) {
    dn[j]     = fmaxf(n32[n0 + 4 * s_q + j], 1e-10f);
    dn[4 + j] = fmaxf(n32[n0 + 16 + 4 * s_q + j], 1e-10f);
  }
  d4 acc0 = {0.0, 0.0, 0.0, 0.0}, acc1 = {0.0, 0.0, 0.0, 0.0};
  {
    float4 a0 = *(const float4*)(F + (size_t)s_ci * NN + n0 + 4 * s_q);
    float4 a1 = *(const float4*)(F + (size_t)s_ci * NN + n0 + 16 + 4 * s_q);
    float4 b[4];
#pragma unroll
    for (int j = 0; j < 4; ++j)
      b[j] = *(const float4*)(cnT + (size_t)s_ci * KK + 16 * s_q + 4 * j);
    float4 w0, w1;
    w0.x = a0.x / dn[0]; w0.y = a0.y / dn[1]; w0.z = a0.z / dn[2]; w0.w = a0.w / dn[3];
    w1.x = a1.x / dn[4]; w1.y = a1.y / dn[5]; w1.z = a1.z / dn[6]; w1.w = a1.w / dn[7];
    *(float4*)&As[0][s_ci][4 * s_q]      = w0;
    *(float4*)&As[0][s_ci][16 + 4 * s_q] = w1;
#pragma unroll
    for (int j = 0; j < 4; ++j)
      *(float4*)&Bs[0][s_ci][16 * s_q + 4 * j] = b[j];
  }
  __syncthreads();

  for (int t = 0; t < NT; ++t) {
    const int buf = t & 1;
    float4 a0, a1, b[4];
    if (t + 1 < NT) {
      const int cb = CK * (t + 1);
      a0 = *(const float4*)(F + (size_t)(cb + s_ci) * NN + n0 + 4 * s_q);
      a1 = *(const float4*)(F + (size_t)(cb + s_ci) * NN + n0 + 16 + 4 * s_q);
#pragma unroll
      for (int j = 0; j < 4; ++j)
        b[j] = *(const float4*)(cnT + (size_t)(cb + s_ci) * KK + 16 * s_q + 4 * j);
    }
#pragma unroll
    for (int s = 0; s < CK / 4; ++s) {
      const int ci = 4 * s + kq;
      double av = (double)As[buf][ci][arow];
      double b0 = (double)Bs[buf][ci][bcol0];
      double b1 = (double)Bs[buf][ci][bcol0 + 16];
      acc0 = __builtin_amdgcn_mfma_f64_16x16x4f64(av, b0, acc0, 0, 0, 0);
      acc1 = __builtin_amdgcn_mfma_f64_16x16x4f64(av, b1, acc1, 0, 0, 0);
    }
    if (t + 1 < NT) {
      const int nb = buf ^ 1;
      float4 w0, w1;
      w0.x = a0.x / dn[0]; w0.y = a0.y / dn[1]; w0.z = a0.z / dn[2]; w0.w = a0.w / dn[3];
      w1.x = a1.x / dn[4]; w1.y = a1.y / dn[5]; w1.z = a1.z / dn[6]; w1.w = a1.w / dn[7];
      *(float4*)&As[nb][s_ci][4 * s_q]      = w0;
      *(float4*)&As[nb][s_ci][16 + 4 * s_q] = w1;
#pragma unroll
      for (int j = 0; j < 4; ++j)
        *(float4*)&Bs[nb][s_ci][16 * s_q + 4 * j] = b[j];
    }
    __syncthreads();
  }

  // epilogue with PROBED D-map
  float* Sl = &As[0][0][0];   // [32][64] f32 scores
#pragma unroll
  for (int r = 0; r < 4; ++r) {
    int iD = rowT[4 * lane + r];
    int jD = colT[4 * lane + r];
    Sl[(h * 16 + iD) * KK + q * 32 + jD]      = (float)acc0[r];
    Sl[(h * 16 + iD) * KK + q * 32 + 16 + jD] = (float)acc1[r];
  }
  __syncthreads();
  if (MODE == 0) {
    if (tid < 32) {
      const float* row = &Sl[tid * KK];
      float best = 1.0f - row[0]; int bk = 0;
      for (int k = 1; k < KK; ++k) { float d = 1.0f - row[k]; if (d < best) { best = d; bk = k; } }
      assign[n0 + tid] = bk;
      atomicAdd(&counts[bk], 1);
    }
  } else {
    for (int idx = tid; idx < 32 * KK; idx += 256) {
      int k = idx >> 5, nj = idx & 31;
      logitsS[(size_t)k * NN + n0 + nj] = Sl[nj * KK + k];
    }
  }
}

// ---- VALU fallback assign (round-1, bit-verified): active iff *okm==0. ----
template <int MODE>
__global__ __launch_bounds__(256) void k_assign_v(const float* __restrict__ F,
                                                  const float* __restrict__ n32,
                                                  const float* __restrict__ cnT,
                                                  int* __restrict__ assign,
                                                  int* __restrict__ counts,
                                                  float* __restrict__ logitsS,
                                                  double* __restrict__ shift,
                                                  const int* __restrict__ done,
                                                  const int* __restrict__ okm,
                                                  int iter) {
  if (*okm != 0) return;
  constexpr int TN = 32, CK = 32, NT = CCH / CK;
  __shared__ __align__(16) float As[2][CK][TN];
  __shared__ __align__(16) float Bs[2][CK][KK];
  const int tid = threadIdx.x;
  if (MODE == 0) {
    if (blockIdx.x == 0 && tid == 0) shift[iter & 1] = 0.0;
    if (*done) return;
  }
  const int n0 = blockIdx.x * TN;
  const int a_ci = tid >> 3, a_nq = tid & 7;
  const int b_ci = tid >> 4, b_kq = tid & 15;
  const int nq = tid & 7, kp = tid >> 3;
  const float* np4 = n32 + n0 + 4 * a_nq;
  float d0 = fmaxf(np4[0], 1e-10f), d1 = fmaxf(np4[1], 1e-10f);
  float d2 = fmaxf(np4[2], 1e-10f), d3 = fmaxf(np4[3], 1e-10f);
  double acc[4][2] = {{0, 0}, {0, 0}, {0, 0}, {0, 0}};
  {
    const float* g0 = cnT + (size_t)(b_ci) * KK + 4 * b_kq;
    const float* g1 = cnT + (size_t)(16 + b_ci) * KK + 4 * b_kq;
    float* l0 = &Bs[0][0][0] + tid * 4;
    float* l1 = &Bs[0][0][0] + 1024 + tid * 4;
    __builtin_amdgcn_global_load_lds((const __attribute__((address_space(1))) void*)g0,
                                     (__attribute__((address_space(3))) void*)l0, 16, 0, 0);
    __builtin_amdgcn_global_load_lds((const __attribute__((address_space(1))) void*)g1,
                                     (__attribute__((address_space(3))) void*)l1, 16, 0, 0);
    float4 va = *(const float4*)(F + (size_t)a_ci * NN + n0 + 4 * a_nq);
    float4 w;
    w.x = va.x / d0; w.y = va.y / d1; w.z = va.z / d2; w.w = va.w / d3;
    *(float4*)(&As[0][0][0] + tid * 4) = w;
  }
  __syncthreads();

  for (int t = 0; t < NT; ++t) {
    const int buf = t & 1, nbuf = buf ^ 1;
    float4 va;
    if (t + 1 < NT) {
      const int cc = CK * (t + 1);
      const float* g0 = cnT + (size_t)(cc + b_ci) * KK + 4 * b_kq;
      const float* g1 = cnT + (size_t)(cc + 16 + b_ci) * KK + 4 * b_kq;
      float* l0 = &Bs[nbuf][0][0] + tid * 4;
      float* l1 = &Bs[nbuf][0][0] + 1024 + tid * 4;
      __builtin_amdgcn_global_load_lds((const __attribute__((address_space(1))) void*)g0,
                                       (__attribute__((address_space(3))) void*)l0, 16, 0, 0);
      __builtin_amdgcn_global_load_lds((const __attribute__((address_space(1))) void*)g1,
                                       (__attribute__((address_space(3))) void*)l1, 16, 0, 0);
      va = *(const float4*)(F + (size_t)(cc + a_ci) * NN + n0 + 4 * a_nq);
    }
#pragma unroll 8
    for (int ci = 0; ci < CK; ++ci) {
      double b0 = (double)Bs[buf][ci][2 * kp + 0], b1 = (double)Bs[buf][ci][2 * kp + 1];
      double a0 = (double)As[buf][ci][4 * nq + 0], a1 = (double)As[buf][ci][4 * nq + 1];
      double a2 = (double)As[buf][ci][4 * nq + 2], a3 = (double)As[buf][ci][4 * nq + 3];
      acc[0][0] = fma(a0, b0, acc[0][0]); acc[0][1] = fma(a0, b1, acc[0][1]);
      acc[1][0] = fma(a1, b0, acc[1][0]); acc[1][1] = fma(a1, b1, acc[1][1]);
      acc[2][0] = fma(a2, b0, acc[2][0]); acc[2][1] = fma(a2, b1, acc[2][1]);
      acc[3][0] = fma(a3, b0, acc[3][0]); acc[3][1] = fma(a3, b1, acc[3][1]);
    }
    if (t + 1 < NT) {
      float4 w;
      w.x = va.x / d0; w.y = va.y / d1; w.z = va.z / d2; w.w = va.w / d3;
      *(float4*)(&As[nbuf][0][0] + tid * 4) = w;
    }
    __syncthreads();
  }

  float* Sl = &Bs[0][0][0];
#pragma unroll
  for (int r = 0; r < 4; ++r) {
    Sl[(4 * nq + r) * KK + 2 * kp + 0] = (float)acc[r][0];
    Sl[(4 * nq + r) * KK + 2 * kp + 1] = (float)acc[r][1];
  }
  __syncthreads();
  if (MODE == 0) {
    if (tid < TN) {
      const float* row = &Sl[tid * KK];
      float best = 1.0f - row[0]; int bk = 0;
      for (int k = 1; k < KK; ++k) { float d = 1.0f - row[k]; if (d < best) { best = d; bk = k; } }
      assign[n0 + tid] = bk;
      atomicAdd(&counts[bk], 1);
    }
  } else {
    for (int idx = tid; idx < TN * KK; idx += 256) {
      int k = idx >> 5, nj = idx & 31;
      logitsS[(size_t)k * NN + n0 + nj] = Sl[nj * KK + k];
    }
  }
}

// per-channel exact f64 segment sum. 1024 blocks x 256. 8-copy LDS bins.
__global__ __launch_bounds__(256) void k_segsum(const float* __restrict__ F,
                                                const int* __restrict__ assign,
                                                double* __restrict__ sums,
                                                const int* __restrict__ done) {
  if (*done) return;
  constexpr int NCOPY = 8, KP = KK + 2;
  __shared__ double bins[NCOPY][KP];
  int c = blockIdx.x, tid = threadIdx.x;
  int cp = tid & (NCOPY - 1);
  for (int idx = tid; idx < NCOPY * KP; idx += 256) (&bins[0][0])[idx] = 0.0;
  __syncthreads();
  for (int n = tid; n < NN; n += 256) {
    int a = assign[n];
    double v = (double)F[(size_t)c * NN + n];
    atomicAdd(&bins[cp][a], v);
  }
  __syncthreads();
  if (tid < KK) {
    double s = 0.0;
#pragma unroll
    for (int r = 0; r < NCOPY; ++r) s += bins[r][tid];
    sums[(size_t)tid * CCH + c] = s;
  }
}

// Fused center update + normalize + shift + counts-zero. 64 blocks x 256.
__global__ __launch_bounds__(256) void k_update(float* __restrict__ centers,
                                                const double* __restrict__ sums,
                                                int* __restrict__ counts,
                                                double* __restrict__ shift,
                                                int* __restrict__ done,
                                                float* __restrict__ cnT,
                                                int iter) {
  __shared__ double red[256];
  int k = blockIdx.x, tid = threadIdx.x;
  bool mydone = false;
  if (iter > 0) {
    double s = shift[(iter - 1) & 1];
    mydone = (*done != 0) || (s * s < TOLV);
  }
  if (mydone) { if (tid == 0) *done = 1; return; }
  int cnt = counts[k];
  double local = 0.0, l2 = 0.0;
  float nc[4];
#pragma unroll
  for (int i = 0; i < 4; ++i) {
    int c = tid + 256 * i;
    float old = centers[k * CCH + c];
    float v = (cnt > 0) ? (float)(sums[k * CCH + c] / (double)cnt) : old;
    nc[i] = v;
    double d = (double)v - (double)old;
    local = fma(d, d, local);
    double dv = (double)v;
    l2 = fma(dv, dv, l2);
    centers[k * CCH + c] = v;
  }
  red[tid] = local; __syncthreads();
  for (int s = 128; s > 0; s >>= 1) { if (tid < s) red[tid] += red[tid + s]; __syncthreads(); }
  if (tid == 0) atomicAdd(&shift[iter & 1], sqrt(red[0]));
  __syncthreads();
  red[tid] = l2; __syncthreads();
  for (int s = 128; s > 0; s >>= 1) { if (tid < s) red[tid] += red[tid + s]; __syncthreads(); }
  float nrm = fmaxf((float)sqrt(red[0]), 1e-10f);
#pragma unroll
  for (int i = 0; i < 4; ++i) {
    int c = tid + 256 * i;
    cnT[(size_t)c * KK + k] = nc[i] / nrm;
  }
  if (tid == 0) counts[k] = 0;
}

// fused bilinear x14 upsample + argmax. 1344 blocks (one per output row) x 256.
__global__ __launch_bounds__(256) void k_upsample(const float* __restrict__ logitsS,
                                                  float* __restrict__ out) {
  __shared__ float P[2][KK][HP];
  const int oy = blockIdx.x;
  const int tid = threadIdx.x;
  const float inv = 1.0f / 14.0f;
  float s_y = ((float)oy + 0.5f) * inv - 0.5f;
  float fy = floorf(s_y);
  float wy1 = s_y - fy, wy0 = 1.0f - wy1;
  int y0 = (int)fy, y1 = y0 + 1;
  if (y0 < 0)      { y0 = 0;      y1 = 0;      wy0 = 1.0f; wy1 = 0.0f; }
  if (y1 > HP - 1) { y0 = HP - 1; y1 = HP - 1; wy0 = 1.0f; wy1 = 0.0f; }
  for (int idx = tid; idx < 2 * KK * HP; idx += 256) {
    int r = idx / (KK * HP);
    int rem = idx - r * (KK * HP);
    int k = rem / HP, x = rem - k * HP;
    P[r][k][x] = logitsS[(size_t)k * NN + (r ? y1 : y0) * HP + x];
  }
  __syncthreads();
  float* outL = out + (size_t)HH * HH;
  const size_t rowoff = (size_t)oy * HH;
  for (int j = 0; j < 6; ++j) {
    int ox = tid + 256 * j;
    if (ox >= HH) break;
    float s_x = ((float)ox + 0.5f) * inv - 0.5f;
    float fx = floorf(s_x);
    float wx1 = s_x - fx, wx0 = 1.0f - wx1;
    int x0 = (int)fx, x1 = x0 + 1;
    if (x0 < 0)      { x0 = 0;      x1 = 0;      wx0 = 1.0f; wx1 = 0.0f; }
    if (x1 > HP - 1) { x0 = HP - 1; x1 = HP - 1; wx0 = 1.0f; wx1 = 0.0f; }
    float best = 0.0f; int bk = 0;
    for (int k = 0; k < KK; ++k) {
      float t0 = fmaf(wy1, P[1][k][x0], wy0 * P[0][k][x0]);
      float t1 = fmaf(wy1, P[1][k][x1], wy0 * P[0][k][x1]);
      float v  = fmaf(wx1, t1, wx0 * t0);
      outL[(size_t)k * (HH * HH) + rowoff + ox] = v;
      if (k == 0 || v > best) { best = v; bk = k; }
    }
    out[rowoff + ox] = (float)bk;
  }
}

extern "C" void kernel_launch(void* const* d_in, const int* in_sizes, int n_in,
                              void* d_out, int out_size, void* d_ws, size_t ws_size,
                              hipStream_t stream) {
  const float* F = (const float*)d_in[0];
  float* out = (float*)d_out;
  char* ws = (char*)d_ws;
  // workspace layout (bytes)
  double*   ssq     = (double*)(ws + 0);         // 9216 d (setup only)
  double*   shift2  = (double*)(ws + 0);         // 2 d — aliases ssq (dead after norm32)
  float*    n32     = (float*)(ws + 73728);      // 9216 f
  float*    centers = (float*)(ws + 110592);     // 64*1024 f
  float*    cnT     = (float*)(ws + 372736);     // 1024*64 f
  double*   sums    = (double*)(ws + 634880);    // 64*1024 d
  float*    logitsS = (float*)(ws + 1159168);    // 64*9216 f
  unsigned* bits1   = (unsigned*)(ws + 3518472);
  unsigned* bits2   = (unsigned*)(ws + 3555336);
  unsigned* perm1   = (unsigned*)(ws + 3592200); // dead after 2nd k_rank
  int*      rowT    = (int*)(ws + 3592208);      // probe tables live in perm1's region
  int*      colT    = (int*)(ws + 3593232);
  int*      okm     = (int*)(ws + 3594256);
  unsigned* perm2   = (unsigned*)(ws + 3629064);
  int*      assign  = (int*)(ws + 3665928);
  int*      counts  = (int*)(ws + 3702792);
  int*      done    = (int*)(ws + 3703048);

  k_rng<<<36, 256, 0, stream>>>(bits1, bits2, ssq);
  k_rank<<<36, 256, 0, stream>>>(bits1, nullptr, perm1);
  k_rank<<<36, 256, 0, stream>>>(bits2, perm1, perm2);
  k_probe<<<1, 64, 0, stream>>>(rowT, colT, okm);   // after perm1 is dead
  k_gather<<<64, 256, 0, stream>>>(F, perm2, centers);
  k_ssq<<<dim3(36, 16), 256, 0, stream>>>(F, ssq);
  k_norm32<<<36, 256, 0, stream>>>(ssq, n32);
  k_prep0<<<64, 256, 0, stream>>>(centers, cnT, counts, shift2, done);

  for (int it = 0; it < NUM_ITERS; ++it) {
    k_assign_m<0><<<288, 256, 0, stream>>>(F, n32, cnT, assign, counts, logitsS, shift2, done, rowT, colT, okm, it);
    k_assign_v<0><<<288, 256, 0, stream>>>(F, n32, cnT, assign, counts, logitsS, shift2, done, okm, it);
    k_segsum<<<1024, 256, 0, stream>>>(F, assign, sums, done);
    k_update<<<64, 256, 0, stream>>>(centers, sums, counts, shift2, done, cnT, it);
  }
  k_assign_m<1><<<288, 256, 0, stream>>>(F, n32, cnT, assign, counts, logitsS, shift2, done, rowT, colT, okm, 0);
  k_assign_v<1><<<288, 256, 0, stream>>>(F, n32, cnT, assign, counts, logitsS, shift2, done, okm, 0);
  k_upsample<<<1344, 256, 0, stream>>>(logitsS, out);
}

// Round 4
// 2582.093 us; speedup vs baseline: 2.0371x; 1.0313x over previous
//
#include <hip/hip_runtime.h>
#include <stdint.h>

#define NN 9216     // tokens = 96*96
#define CCH 1024    // channels
#define KK 64       // clusters
#define HP 96       // patch grid
#define SCALE 14
#define HH 1344     // output H=W
#define NUM_ITERS 30
#define TOLV 1e-4

typedef __attribute__((ext_vector_type(4))) double d4;

// ---------------- Threefry-2x32-20 block ----------------
__device__ __forceinline__ void tf2x32(unsigned k0, unsigned k1, unsigned& x0, unsigned& x1) {
  unsigned ks2 = k0 ^ k1 ^ 0x1BD11BDAu;
  x0 += k0; x1 += k1;
#define TFR(r) { x0 += x1; x1 = (x1 << r) | (x1 >> (32 - r)); x1 ^= x0; }
  TFR(13) TFR(15) TFR(26) TFR(6)
  x0 += k1; x1 += ks2 + 1u;
  TFR(17) TFR(29) TFR(16) TFR(24)
  x0 += ks2; x1 += k0 + 2u;
  TFR(13) TFR(15) TFR(26) TFR(6)
  x0 += k0; x1 += k1 + 3u;
  TFR(17) TFR(29) TFR(16) TFR(24)
  x0 += k1; x1 += ks2 + 4u;
  TFR(13) TFR(15) TFR(26) TFR(6)
  x0 += ks2; x1 += k0 + 5u;
#undef TFR
}

// Fused threefry-bits + stable-sort rank. WHICH=1: subkey1 (perm over identity);
// WHICH=2: subkey2 (perm gathering vals). 36 blocks x 256.
template <int WHICH>
__global__ __launch_bounds__(256) void k_rank(const unsigned* __restrict__ vals,
                                              unsigned* __restrict__ out_perm) {
  __shared__ __align__(16) unsigned lb[NN];
  int tid = threadIdx.x;
  // derive subkey (jax_threefry_partitionable): key1=blk(key0;0,0); sub_i=blk(key_i;0,1)
  unsigned sa, sb;
  if (WHICH == 1) { sa = 0; sb = 1; tf2x32(0u, 42u, sa, sb); }
  else {
    unsigned k1a = 0, k1b = 0; tf2x32(0u, 42u, k1a, k1b);
    sa = 0; sb = 1; tf2x32(k1a, k1b, sa, sb);
  }
  for (int idx = tid; idx < NN; idx += 256) {
    unsigned o0 = 0, o1 = (unsigned)idx;
    tf2x32(sa, sb, o0, o1);
    lb[idx] = o0 ^ o1;
  }
  __syncthreads();
  int i = blockIdx.x * 256 + tid;
  unsigned kb = lb[i];
  const uint4* l4 = reinterpret_cast<const uint4*>(lb);
  int rank = 0;
  for (int jj = 0; jj < NN / 4; ++jj) {
    uint4 v = l4[jj];
    int j = jj * 4;
    rank += (v.x < kb) || (v.x == kb && (j + 0) < i);
    rank += (v.y < kb) || (v.y == kb && (j + 1) < i);
    rank += (v.z < kb) || (v.z == kb && (j + 2) < i);
    rank += (v.w < kb) || (v.w == kb && (j + 3) < i);
  }
  out_perm[rank] = vals ? vals[i] : (unsigned)i;
}

// deterministic f64 partial sums of squares. grid (36,16) x 256. No atomics.
__global__ __launch_bounds__(256) void k_ssq(const float* __restrict__ F, double* __restrict__ ssq_p) {
  int n = blockIdx.x * 256 + threadIdx.x;
  int c0 = blockIdx.y * 64;
  double acc = 0.0;
#pragma unroll 4
  for (int ci = 0; ci < 64; ++ci) {
    double v = (double)F[(size_t)(c0 + ci) * NN + n];
    acc = fma(v, v, acc);
  }
  ssq_p[(size_t)blockIdx.y * NN + n] = acc;
}

// combine 16 partials -> correctly-rounded f32 norm per token. 36 blocks x 256.
__global__ __launch_bounds__(256) void k_norm16(const double* __restrict__ ssq_p, float* __restrict__ n32) {
  int n = blockIdx.x * 256 + threadIdx.x;
  double acc = 0.0;
#pragma unroll
  for (int r = 0; r < 16; ++r) acc += ssq_p[(size_t)r * NN + n];
  n32[n] = (float)sqrt(acc);
}

// Fused gather + one-time init: centers0[k]=X[perm2[k]]; cnT; zero counts/shift/done.
// Norm accumulation order identical to old prep0 (c = tid + 256*i ascending). 64 blocks.
__global__ __launch_bounds__(256) void k_prep0(const float* __restrict__ F,
                                               const unsigned* __restrict__ perm2,
                                               float* __restrict__ centers,
                                               float* __restrict__ cnT,
                                               int* __restrict__ counts,
                                               double* __restrict__ shift,
                                               int* __restrict__ done) {
  __shared__ double red[256];
  int k = blockIdx.x, tid = threadIdx.x;
  unsigned n = perm2[k];
  double local = 0.0;
  float cv[4];
#pragma unroll
  for (int i = 0; i < 4; ++i) {
    int c = tid + 256 * i;
    float v = F[(size_t)c * NN + n];
    cv[i] = v;
    centers[k * CCH + c] = v;
    double dv = (double)v;
    local = fma(dv, dv, local);
  }
  red[tid] = local; __syncthreads();
  for (int s = 128; s > 0; s >>= 1) { if (tid < s) red[tid] += red[tid + s]; __syncthreads(); }
  float nc = fmaxf((float)sqrt(red[0]), 1e-10f);
#pragma unroll
  for (int i = 0; i < 4; ++i) {
    int c = tid + 256 * i;
    cnT[(size_t)c * KK + k] = cv[i] / nc;   // f32 division, like reference
  }
  if (tid == 0) {
    counts[k] = 0;
    if (k == 0) { *done = 0; shift[0] = 0.0; shift[1] = 0.0; }
  }
}

// ---- MFMA f64 layout probe (1 block x 64). Exact power-of-2 probes discover the
// D-element -> (row,col) map; okm=1 iff all probes decode (HW-deterministic; round-3
// confirmed this path active & correct on gfx950). ----
__global__ void k_probe(int* __restrict__ rowT, int* __restrict__ colT, int* __restrict__ okm) {
  int l = threadIdx.x;
  d4 z = {0.0, 0.0, 0.0, 0.0};
  d4 v1 = __builtin_amdgcn_mfma_f64_16x16x4f64(ldexp(1.0, l), 1.0, z, 0, 0, 0);
  d4 v2 = __builtin_amdgcn_mfma_f64_16x16x4f64(1.0, ldexp(1.0, l), z, 0, 0, 0);
  d4 v3 = __builtin_amdgcn_mfma_f64_16x16x4f64(ldexp(1.0, l >> 4), ldexp(1.0, 10 * (l >> 4)), z, 0, 0, 0);
  const double CM = 281479271743489.0;      // 1+2^16+2^32+2^48 (exact)
  const double P3 = 8594130945.0;           // 1+2^11+2^22+2^33 (exact)
  bool good = true;
#pragma unroll
  for (int r = 0; r < 4; ++r) {
    int i = -1, j = -1;
    for (int t = 0; t < 16; ++t) {
      if (v1[r] == ldexp(CM, t)) i = t;
      if (v2[r] == ldexp(CM, t)) j = t;
    }
    good = good && (i >= 0) && (j >= 0) && (v3[r] == P3);
    rowT[4 * l + r] = i; colT[4 * l + r] = j;
  }
  unsigned long long mg = __ballot(good);
  if (l == 0) *okm = (mg == ~0ull) ? 1 : 0;
}

// scores[n][k] = Xn32[n]·cn32[k] via f64 MFMA, exact f64 accumulation of f32-rounded
// inputs (f32 divide in staging = reference Xn rounding). 192 blocks x 48 tokens:
// <=1 block/CU (no serialization tail). 4 waves; wave w = 48 tokens x 16 clusters
// (3 independent MFMA chains -> latency hidden). LDS padded strides: 2-way bank
// alias max (free). D placed via probed map. MODE0: argmin->assign+counts.
// MODE1: logitsS[k][n].
template <int MODE>
__global__ __launch_bounds__(256) void k_assign(const float* __restrict__ F,
                                                const float* __restrict__ n32,
                                                const float* __restrict__ cnT,
                                                int* __restrict__ assign,
                                                int* __restrict__ counts,
                                                float* __restrict__ logitsS,
                                                double* __restrict__ shift,
                                                const int* __restrict__ done,
                                                const int* __restrict__ rowT,
                                                const int* __restrict__ colT,
                                                const int* __restrict__ okm,
                                                int iter) {
  constexpr int TN = 48, CK = 64, NT = CCH / CK;   // 16 channel-tiles
  constexpr int ASTR = 56, BSTR = 72;              // padded strides (floats)
  __shared__ __align__(16) float As[2][CK][ASTR];  // 28 KB
  __shared__ __align__(16) float Bs[2][CK][BSTR];  // 36 KB
  const int tid = threadIdx.x;
  if (*okm == 0) return;
  if (MODE == 0) {
    if (blockIdx.x == 0 && tid == 0) shift[iter & 1] = 0.0;
    if (*done) return;
  }
  const int n0 = blockIdx.x * TN;
  // staging mapping
  const int s_ci = tid >> 2, s_q = tid & 3;
  // compute mapping: wave w -> clusters [16w,16w+16), 3 M-tiles of tokens
  const int lane = tid & 63, w = tid >> 6;
  const int col = lane & 15, kq = lane >> 4;
  const int bcol = 16 * w + col;
  float dn[12];
#pragma unroll
  for (int m = 0; m < 3; ++m)
#pragma unroll
    for (int j = 0; j < 4; ++j)
      dn[4 * m + j] = fmaxf(n32[n0 + 16 * m + 4 * s_q + j], 1e-10f);
  d4 acc[3] = {{0,0,0,0},{0,0,0,0},{0,0,0,0}};

  // ---- prologue: stage tile 0 into buffer 0 ----
  {
    float4 a[3], b[4];
#pragma unroll
    for (int m = 0; m < 3; ++m)
      a[m] = *(const float4*)(F + (size_t)s_ci * NN + n0 + 16 * m + 4 * s_q);
#pragma unroll
    for (int j = 0; j < 4; ++j)
      b[j] = *(const float4*)(cnT + (size_t)s_ci * KK + 16 * s_q + 4 * j);
#pragma unroll
    for (int m = 0; m < 3; ++m) {
      float4 ww;
      ww.x = a[m].x / dn[4*m+0]; ww.y = a[m].y / dn[4*m+1];
      ww.z = a[m].z / dn[4*m+2]; ww.w = a[m].w / dn[4*m+3];
      *(float4*)&As[0][s_ci][16 * m + 4 * s_q] = ww;
    }
#pragma unroll
    for (int j = 0; j < 4; ++j)
      *(float4*)&Bs[0][s_ci][16 * s_q + 4 * j] = b[j];
  }
  __syncthreads();

  for (int t = 0; t < NT; ++t) {
    const int buf = t & 1;
    float4 a[3], b[4];
    if (t + 1 < NT) {   // issue next-tile loads; latency hides under MFMA
      const int cb = CK * (t + 1);
#pragma unroll
      for (int m = 0; m < 3; ++m)
        a[m] = *(const float4*)(F + (size_t)(cb + s_ci) * NN + n0 + 16 * m + 4 * s_q);
#pragma unroll
      for (int j = 0; j < 4; ++j)
        b[j] = *(const float4*)(cnT + (size_t)(cb + s_ci) * KK + 16 * s_q + 4 * j);
    }
#pragma unroll
    for (int s = 0; s < CK / 4; ++s) {       // 16 K-steps of K=4
      const int ci = 4 * s + kq;
      double bv = (double)Bs[buf][ci][bcol];
      double a0 = (double)As[buf][ci][col];
      double a1 = (double)As[buf][ci][16 + col];
      double a2 = (double)As[buf][ci][32 + col];
      acc[0] = __builtin_amdgcn_mfma_f64_16x16x4f64(a0, bv, acc[0], 0, 0, 0);
      acc[1] = __builtin_amdgcn_mfma_f64_16x16x4f64(a1, bv, acc[1], 0, 0, 0);
      acc[2] = __builtin_amdgcn_mfma_f64_16x16x4f64(a2, bv, acc[2], 0, 0, 0);
    }
    if (t + 1 < NT) {
      const int nb = buf ^ 1;
#pragma unroll
      for (int m = 0; m < 3; ++m) {
        float4 ww;
        ww.x = a[m].x / dn[4*m+0]; ww.y = a[m].y / dn[4*m+1];
        ww.z = a[m].z / dn[4*m+2]; ww.w = a[m].w / dn[4*m+3];
        *(float4*)&As[nb][s_ci][16 * m + 4 * s_q] = ww;
      }
#pragma unroll
      for (int j = 0; j < 4; ++j)
        *(float4*)&Bs[nb][s_ci][16 * s_q + 4 * j] = b[j];
    }
    __syncthreads();
  }

  // epilogue with probed D-map: Sl[48][64] f32 overlays As[0] (12 KB < 14 KB)
  float* Sl = &As[0][0][0];
#pragma unroll
  for (int r = 0; r < 4; ++r) {
    int iD = rowT[4 * lane + r];
    int jD = colT[4 * lane + r];
#pragma unroll
    for (int m = 0; m < 3; ++m)
      Sl[(16 * m + iD) * KK + 16 * w + jD] = (float)acc[m][r];
  }
  __syncthreads();
  if (MODE == 0) {
    if (tid < TN) {
      const float* row = &Sl[tid * KK];
      float best = 1.0f - row[0]; int bk = 0;   // f32 "1-sim": ties -> first index
      for (int k = 1; k < KK; ++k) { float d = 1.0f - row[k]; if (d < best) { best = d; bk = k; } }
      assign[n0 + tid] = bk;
      atomicAdd(&counts[bk], 1);
    }
  } else {
    for (int idx = tid; idx < TN * KK; idx += 256) {
      int k = idx / TN, nj = idx - k * TN;
      logitsS[(size_t)k * NN + n0 + nj] = Sl[nj * KK + k];
    }
  }
}

// per-channel exact f64 segment sum. 1024 blocks x 256. 8-copy LDS bins.
__global__ __launch_bounds__(256) void k_segsum(const float* __restrict__ F,
                                                const int* __restrict__ assign,
                                                double* __restrict__ sums,
                                                const int* __restrict__ done) {
  if (*done) return;
  constexpr int NCOPY = 8, KP = KK + 2;
  __shared__ double bins[NCOPY][KP];
  int c = blockIdx.x, tid = threadIdx.x;
  int cp = tid & (NCOPY - 1);
  for (int idx = tid; idx < NCOPY * KP; idx += 256) (&bins[0][0])[idx] = 0.0;
  __syncthreads();
  for (int n = tid; n < NN; n += 256) {
    int a = assign[n];
    double v = (double)F[(size_t)c * NN + n];
    atomicAdd(&bins[cp][a], v);
  }
  __syncthreads();
  if (tid < KK) {
    double s = 0.0;
#pragma unroll
    for (int r = 0; r < NCOPY; ++r) s += bins[r][tid];
    sums[(size_t)tid * CCH + c] = s;
  }
}

// Fused center update + normalize + shift + counts-zero. 64 blocks x 256.
// Freeze uses shift from the PREVIOUS iteration (scan semantics); done latches.
__global__ __launch_bounds__(256) void k_update(float* __restrict__ centers,
                                                const double* __restrict__ sums,
                                                int* __restrict__ counts,
                                                double* __restrict__ shift,
                                                int* __restrict__ done,
                                                float* __restrict__ cnT,
                                                int iter) {
  __shared__ double red[256];
  int k = blockIdx.x, tid = threadIdx.x;
  bool mydone = false;
  if (iter > 0) {
    double s = shift[(iter - 1) & 1];
    mydone = (*done != 0) || (s * s < TOLV);
  }
  if (mydone) { if (tid == 0) *done = 1; return; }
  int cnt = counts[k];
  double local = 0.0, l2 = 0.0;
  float nc[4];
#pragma unroll
  for (int i = 0; i < 4; ++i) {
    int c = tid + 256 * i;
    float old = centers[k * CCH + c];
    float v = (cnt > 0) ? (float)(sums[k * CCH + c] / (double)cnt) : old;
    nc[i] = v;
    double d = (double)v - (double)old;
    local = fma(d, d, local);
    double dv = (double)v;
    l2 = fma(dv, dv, l2);
    centers[k * CCH + c] = v;
  }
  red[tid] = local; __syncthreads();
  for (int s = 128; s > 0; s >>= 1) { if (tid < s) red[tid] += red[tid + s]; __syncthreads(); }
  if (tid == 0) atomicAdd(&shift[iter & 1], sqrt(red[0]));
  __syncthreads();
  red[tid] = l2; __syncthreads();
  for (int s = 128; s > 0; s >>= 1) { if (tid < s) red[tid] += red[tid + s]; __syncthreads(); }
  float nrm = fmaxf((float)sqrt(red[0]), 1e-10f);
#pragma unroll
  for (int i = 0; i < 4; ++i) {
    int c = tid + 256 * i;
    cnT[(size_t)c * KK + k] = nc[i] / nrm;
  }
  if (tid == 0) counts[k] = 0;
}

// fused bilinear x14 upsample + argmax. 1344 blocks (one per output row) x 256.
__global__ __launch_bounds__(256) void k_upsample(const float* __restrict__ logitsS,
                                                  float* __restrict__ out) {
  __shared__ float P[2][KK][HP];
  const int oy = blockIdx.x;
  const int tid = threadIdx.x;
  const float inv = 1.0f / 14.0f;
  float s_y = ((float)oy + 0.5f) * inv - 0.5f;
  float fy = floorf(s_y);
  float wy1 = s_y - fy, wy0 = 1.0f - wy1;
  int y0 = (int)fy, y1 = y0 + 1;
  if (y0 < 0)      { y0 = 0;      y1 = 0;      wy0 = 1.0f; wy1 = 0.0f; }
  if (y1 > HP - 1) { y0 = HP - 1; y1 = HP - 1; wy0 = 1.0f; wy1 = 0.0f; }
  for (int idx = tid; idx < 2 * KK * HP; idx += 256) {
    int r = idx / (KK * HP);
    int rem = idx - r * (KK * HP);
    int k = rem / HP, x = rem - k * HP;
    P[r][k][x] = logitsS[(size_t)k * NN + (r ? y1 : y0) * HP + x];
  }
  __syncthreads();
  float* outL = out + (size_t)HH * HH;
  const size_t rowoff = (size_t)oy * HH;
  for (int j = 0; j < 6; ++j) {
    int ox = tid + 256 * j;
    if (ox >= HH) break;
    float s_x = ((float)ox + 0.5f) * inv - 0.5f;
    float fx = floorf(s_x);
    float wx1 = s_x - fx, wx0 = 1.0f - wx1;
    int x0 = (int)fx, x1 = x0 + 1;
    if (x0 < 0)      { x0 = 0;      x1 = 0;      wx0 = 1.0f; wx1 = 0.0f; }
    if (x1 > HP - 1) { x0 = HP - 1; x1 = HP - 1; wx0 = 1.0f; wx1 = 0.0f; }
    float best = 0.0f; int bk = 0;
    for (int k = 0; k < KK; ++k) {
      float t0 = fmaf(wy1, P[1][k][x0], wy0 * P[0][k][x0]);
      float t1 = fmaf(wy1, P[1][k][x1], wy0 * P[0][k][x1]);
      float v  = fmaf(wx1, t1, wx0 * t0);
      outL[(size_t)k * (HH * HH) + rowoff + ox] = v;
      if (k == 0 || v > best) { best = v; bk = k; }
    }
    out[rowoff + ox] = (float)bk;
  }
}

extern "C" void kernel_launch(void* const* d_in, const int* in_sizes, int n_in,
                              void* d_out, int out_size, void* d_ws, size_t ws_size,
                              hipStream_t stream) {
  const float* F = (const float*)d_in[0];
  float* out = (float*)d_out;
  char* ws = (char*)d_ws;
  // workspace layout (bytes)
  double*   shift2  = (double*)(ws + 0);         // 2 d (old ssq region, free)
  float*    n32     = (float*)(ws + 73728);      // 9216 f
  float*    centers = (float*)(ws + 110592);     // 64*1024 f
  float*    cnT     = (float*)(ws + 372736);     // 1024*64 f
  double*   sums    = (double*)(ws + 634880);    // 64*1024 d
  float*    logitsS = (float*)(ws + 1159168);    // 64*9216 f (used only at the end)
  double*   ssq_p   = (double*)(ws + 1159168);   // 16*9216 d = 1.18 MB, ALIASES logitsS (setup only)
  unsigned* perm1   = (unsigned*)(ws + 3592200); // dead after 2nd k_rank
  int*      rowT    = (int*)(ws + 3592208);      // probe tables reuse perm1's region
  int*      colT    = (int*)(ws + 3593232);
  int*      okm     = (int*)(ws + 3594256);
  unsigned* perm2   = (unsigned*)(ws + 3629064);
  int*      assign  = (int*)(ws + 3665928);
  int*      counts  = (int*)(ws + 3702792);
  int*      done    = (int*)(ws + 3703048);

  k_rank<1><<<36, 256, 0, stream>>>(nullptr, perm1);
  k_rank<2><<<36, 256, 0, stream>>>(perm1, perm2);
  k_probe<<<1, 64, 0, stream>>>(rowT, colT, okm);   // after perm1 is dead
  k_ssq<<<dim3(36, 16), 256, 0, stream>>>(F, ssq_p);
  k_norm16<<<36, 256, 0, stream>>>(ssq_p, n32);
  k_prep0<<<64, 256, 0, stream>>>(F, perm2, centers, cnT, counts, shift2, done);

  for (int it = 0; it < NUM_ITERS; ++it) {
    k_assign<0><<<192, 256, 0, stream>>>(F, n32, cnT, assign, counts, logitsS, shift2, done, rowT, colT, okm, it);
    k_segsum<<<1024, 256, 0, stream>>>(F, assign, sums, done);
    k_update<<<64, 256, 0, stream>>>(centers, sums, counts, shift2, done, cnT, it);
  }
  k_assign<1><<<192, 256, 0, stream>>>(F, n32, cnT, assign, counts, logitsS, shift2, done, rowT, colT, okm, 0);
  k_upsample<<<1344, 256, 0, stream>>>(logitsS, out);
}